// Round 8
// baseline (470.870 us; speedup 1.0000x reference)
//
#include <hip/hip_runtime.h>
#include <hip/hip_bf16.h>
#include <math.h>

#define B_ 64
#define N_ 1024
#define E_ 524288
#define K1_ 512
#define K2_ 256
#define K3_ 128
#define M0_ 65536
#define M1_ 32768
#define M2_ 16384
#define M3_ 8192

static __device__ __forceinline__ float eluf(float x){ return x > 0.f ? x : expm1f(x); }
static __device__ __forceinline__ float4 elu4(float4 v){
  float4 o; o.x=eluf(v.x); o.y=eluf(v.y); o.z=eluf(v.z); o.w=eluf(v.w); return o;
}

// Tiled GEMM, BM x BN block, 256 threads, register prefetch + double-buffered
// LDS (one barrier per K-step). Row-major Xs[BM][36] (float4 staging writes,
// broadcast scalar reads — 0 bank conflicts, round-6 verified). RM = 4.
// MODE 0: H = X @ W
// MODE 1: H = elu(X[perm[m]]*vals[m]) @ W        (fused top-k pool gather)
// MODE 2: H = elu(concat(Xd via rm/orig, Xs)) @ W (fused unpool+concat)
template<int BM,int BN,int MODE>
__global__ __launch_bounds__(256) void k_mm(const float* __restrict__ X,
    const float* __restrict__ W, float* __restrict__ H, int M, int K, int N,
    const int* __restrict__ perm, const float* __restrict__ vals,
    const float* __restrict__ Xd, const int* __restrict__ orig,
    const int* __restrict__ rm, int WD4){
  constexpr int TX = BN/4;
  constexpr int TY = 256/TX;
  constexpr int RM = BM/TY;          // = 4
  constexpr int XLD = BM/32;         // float4 X loads / thread / step
  constexpr int WLD = BN/32;         // float4 W loads / thread / step
  __shared__ float Xs[2][BM][36];
  __shared__ float Ws[2][32][BN];
  const int t = threadIdx.x;
  const int tx = t % TX, ty = t / TX;
  const int m0 = blockIdx.x*BM, n0 = blockIdx.y*BN;
  float4 xr[XLD], wr[WLD];
  float acc[RM][4];
  #pragma unroll
  for (int r=0;r<RM;++r){acc[r][0]=0.f;acc[r][1]=0.f;acc[r][2]=0.f;acc[r][3]=0.f;}

  auto load_step = [&](int k0){
    #pragma unroll
    for (int l=0;l<XLD;++l){
      int fi=l*256+t, row=fi>>3, q=fi&7;
      int m = m0+row;
      int c4 = (k0>>2)+q;
      float4 v;
      if (MODE==0){
        v = *(const float4*)(X + (size_t)m*K + (c4<<2));
      } else if (MODE==1){
        int pm = perm[m]; float vv = vals[m];
        float4 h = *(const float4*)(X + (size_t)pm*K + (c4<<2));
        v.x=eluf(h.x*vv); v.y=eluf(h.y*vv); v.z=eluf(h.z*vv); v.w=eluf(h.w*vv);
      } else {
        if (c4 < WD4){
          int o = orig ? orig[m] : m;
          int j = rm[o];
          if (j>=0) v = elu4(*(const float4*)(Xd + ((size_t)j*WD4 + c4)*4));
          else { v.x=0.f;v.y=0.f;v.z=0.f;v.w=0.f; }
        } else {
          int ws4 = (K>>2) - WD4;
          v = elu4(*(const float4*)(X + ((size_t)m*ws4 + (c4-WD4))*4));
        }
      }
      xr[l]=v;
    }
    #pragma unroll
    for (int l=0;l<WLD;++l){
      int fi=l*256+t, wrow=fi/(BN/4), wq=fi%(BN/4);
      wr[l] = *(const float4*)(W + (size_t)(k0+wrow)*N + n0 + wq*4);
    }
  };
  auto commit = [&](int buf){
    #pragma unroll
    for (int l=0;l<XLD;++l){
      int fi=l*256+t, row=fi>>3, q=fi&7;
      *(float4*)(&Xs[buf][row][q*4]) = xr[l];
    }
    #pragma unroll
    for (int l=0;l<WLD;++l){
      int fi=l*256+t, wrow=fi/(BN/4), wq=fi%(BN/4);
      *(float4*)(&Ws[buf][wrow][wq*4]) = wr[l];
    }
  };

  load_step(0);
  commit(0);
  __syncthreads();
  int cur = 0;
  for (int k0=0;k0<K;k0+=32){
    const bool hasNext = (k0+32 < K);
    if (hasNext) load_step(k0+32);     // global loads in flight during FMAs
    #pragma unroll
    for (int kk=0;kk<32;++kk){
      float4 wv = *(const float4*)(&Ws[cur][kk][tx*4]);
      #pragma unroll
      for (int r=0;r<RM;++r){
        float xv = Xs[cur][ty*RM+r][kk];
        acc[r][0]=fmaf(xv,wv.x,acc[r][0]);
        acc[r][1]=fmaf(xv,wv.y,acc[r][1]);
        acc[r][2]=fmaf(xv,wv.z,acc[r][2]);
        acc[r][3]=fmaf(xv,wv.w,acc[r][3]);
      }
    }
    if (hasNext){
      commit(cur^1);                   // write the OTHER buffer: no race with readers
      __syncthreads();                 // single barrier per K-step
      cur ^= 1;
    }
  }
  #pragma unroll
  for (int r=0;r<RM;++r){
    int m = m0 + ty*RM + r;
    float4 h; h.x=acc[r][0];h.y=acc[r][1];h.z=acc[r][2];h.w=acc[r][3];
    *(float4*)(H + (size_t)m*N + n0 + tx*4) = h;
  }
}

// ---- level-0 CSR build (spread atomics only) ----
__global__ void k_deg0(const int* __restrict__ dst, int* __restrict__ degi){
  int i = blockIdx.x*256+threadIdx.x; if (i>=E_) return;
  atomicAdd(&degi[dst[i]], 1);
}
__global__ void k_place0(const int* __restrict__ src, const int* __restrict__ dst,
                         int* __restrict__ cursor, int* __restrict__ col){
  int i = blockIdx.x*256+threadIdx.x; if (i>=E_) return;
  int p = atomicAdd(&cursor[dst[i]], 1);
  col[p] = src[i];
}

// ---- hierarchical scan over M0 degrees ----
__global__ __launch_bounds__(256) void k_scanA(const int* __restrict__ degi,
                                               int* __restrict__ bsum){
  __shared__ int ls[256];
  int b = blockIdx.x, t = threadIdx.x;
  ls[t] = degi[b*256+t]; __syncthreads();
  for (int o=128;o>0;o>>=1){ if (t<o) ls[t]+=ls[t+o]; __syncthreads(); }
  if (t==0) bsum[b] = ls[0];
}
__global__ __launch_bounds__(256) void k_scanB(int* __restrict__ bsum){
  __shared__ int ps[256];
  int t = threadIdx.x;
  ps[t] = bsum[t]; __syncthreads();
  for (int o=1;o<256;o<<=1){
    int v = (t>=o) ? ps[t-o] : 0;
    __syncthreads(); ps[t]+=v; __syncthreads();
  }
  bsum[t] = ps[t];
}
__global__ __launch_bounds__(256) void k_scanC(const int* __restrict__ degi,
    const int* __restrict__ bsum, int* __restrict__ rowptr,
    int* __restrict__ cursor, float* __restrict__ dinv){
  __shared__ int ps[256];
  int b = blockIdx.x, t = threadIdx.x;
  int i = b*256+t;
  int d = degi[i];
  ps[t] = d; __syncthreads();
  for (int o=1;o<256;o<<=1){
    int v = (t>=o) ? ps[t-o] : 0;
    __syncthreads(); ps[t]+=v; __syncthreads();
  }
  int off = (b==0 ? 0 : bsum[b-1]) + ps[t] - d;
  rowptr[i] = off; cursor[i] = off;
  dinv[i] = rsqrtf((float)d + 2.f);
  if (i == M0_-1) rowptr[M0_] = off + d;
}

// pooled-level degree via rm-filtered level-0 CSR
__global__ void k_deg_orig(const int* __restrict__ orig, const int* __restrict__ rowptr0,
                           const int* __restrict__ col0, const int* __restrict__ rm,
                           float* __restrict__ dinv, int M){
  int i = blockIdx.x*256+threadIdx.x; if (i>=M) return;
  int o = orig[i];
  int beg = rowptr0[o], end = rowptr0[o+1];
  int d = 0;
  for (int j=beg;j<end;++j) d += (rm[col0[j]] >= 0) ? 1 : 0;
  dinv[i] = rsqrtf((float)d + 2.f);
}

__global__ void k_compose_idx(const int* __restrict__ prevOrig, const int* __restrict__ idxL,
                              int* __restrict__ origL, int n){
  int i = blockIdx.x*256+threadIdx.x; if (i<n) origL[i] = prevOrig[idxL[i]];
}

// ---- level-0 GCN aggregation; optional fused pool-score output
template<int F, bool SCORE>
__global__ __launch_bounds__(256) void k_gather(const int* __restrict__ rowptr,
    const int* __restrict__ col, const float* __restrict__ dinv,
    const float* __restrict__ H, const float* __restrict__ bias,
    float* __restrict__ OUT, int M,
    const float* __restrict__ p, float* __restrict__ score){
  constexpr int FQ = F/4;
  int i = blockIdx.x*256+threadIdx.x;
  if (i >= M*FQ) return;
  int n = i/FQ, q = i - (i/FQ)*FQ;
  int beg = rowptr[n], end = rowptr[n+1];
  float4 acc; acc.x=0.f;acc.y=0.f;acc.z=0.f;acc.w=0.f;
  for (int j=beg;j<end;++j){
    int s = col[j];
    float c = dinv[s];
    float4 h = *(const float4*)(H + (size_t)s*F + q*4);
    acc.x=fmaf(c,h.x,acc.x); acc.y=fmaf(c,h.y,acc.y);
    acc.z=fmaf(c,h.z,acc.z); acc.w=fmaf(c,h.w,acc.w);
  }
  float dn = dinv[n];
  float sc = 2.f*dn*dn;
  float4 hn = *(const float4*)(H + (size_t)n*F + q*4);
  float4 bv = *(const float4*)(bias + q*4);
  float4 o;
  o.x = eluf(fmaf(sc,hn.x,fmaf(dn,acc.x,bv.x)));
  o.y = eluf(fmaf(sc,hn.y,fmaf(dn,acc.y,bv.y)));
  o.z = eluf(fmaf(sc,hn.z,fmaf(dn,acc.z,bv.z)));
  o.w = eluf(fmaf(sc,hn.w,fmaf(dn,acc.w,bv.w)));
  *(float4*)(OUT + (size_t)n*F + q*4) = o;
  if (SCORE){
    float4 pv = *(const float4*)(p + q*4);
    float dot = o.x*pv.x + o.y*pv.y + o.z*pv.z + o.w*pv.w;
    float n2  = pv.x*pv.x + pv.y*pv.y + pv.z*pv.z + pv.w*pv.w;
    #pragma unroll
    for (int mk=FQ>>1; mk>0; mk>>=1){
      dot += __shfl_xor(dot, mk);
      n2  += __shfl_xor(n2,  mk);
    }
    if (q==0) score[n] = tanhf(dot * rsqrtf(n2));
  }
}

// ---- pooled-level GCN aggregation through rm filter; optional fused score
template<int F, bool SCORE>
__global__ __launch_bounds__(256) void k_gather_rm(const int* __restrict__ orig,
    const int* __restrict__ rowptr0, const int* __restrict__ col0,
    const int* __restrict__ rm, const float* __restrict__ dinv,
    const float* __restrict__ H, const float* __restrict__ bias,
    float* __restrict__ OUT, int M,
    const float* __restrict__ p, float* __restrict__ score){
  constexpr int FQ = F/4;
  int i = blockIdx.x*256+threadIdx.x;
  if (i >= M*FQ) return;
  int n = i/FQ, q = i - (i/FQ)*FQ;
  int o = orig[n];
  int beg = rowptr0[o], end = rowptr0[o+1];
  float4 acc; acc.x=0.f;acc.y=0.f;acc.z=0.f;acc.w=0.f;
  for (int j=beg;j<end;++j){
    int s = rm[col0[j]];
    if (s >= 0){
      float c = dinv[s];
      float4 h = *(const float4*)(H + (size_t)s*F + q*4);
      acc.x=fmaf(c,h.x,acc.x); acc.y=fmaf(c,h.y,acc.y);
      acc.z=fmaf(c,h.z,acc.z); acc.w=fmaf(c,h.w,acc.w);
    }
  }
  float dn = dinv[n];
  float sc = 2.f*dn*dn;
  float4 hn = *(const float4*)(H + (size_t)n*F + q*4);
  float4 bv = *(const float4*)(bias + q*4);
  float4 ov;
  ov.x = eluf(fmaf(sc,hn.x,fmaf(dn,acc.x,bv.x)));
  ov.y = eluf(fmaf(sc,hn.y,fmaf(dn,acc.y,bv.y)));
  ov.z = eluf(fmaf(sc,hn.z,fmaf(dn,acc.z,bv.z)));
  ov.w = eluf(fmaf(sc,hn.w,fmaf(dn,acc.w,bv.w)));
  *(float4*)(OUT + (size_t)n*F + q*4) = ov;
  if (SCORE){
    float4 pv = *(const float4*)(p + q*4);
    float dot = ov.x*pv.x + ov.y*pv.y + ov.z*pv.z + ov.w*pv.w;
    float n2  = pv.x*pv.x + pv.y*pv.y + pv.z*pv.z + pv.w*pv.w;
    #pragma unroll
    for (int mk=FQ>>1; mk>0; mk>>=1){
      dot += __shfl_xor(dot, mk);
      n2  += __shfl_xor(n2,  mk);
    }
    if (q==0) score[n] = tanhf(dot * rsqrtf(n2));
  }
}

// block g sorts its npg scores descending (tie: lower index first), writes top-K
__global__ void k_topk(const float* __restrict__ score, int npg, int K,
                       int* __restrict__ perm, float* __restrict__ vals){
  __shared__ float ss[1024]; __shared__ int si[1024];
  int g = blockIdx.x, tid = threadIdx.x;
  ss[tid] = score[g*npg + tid]; si[tid] = tid;
  __syncthreads();
  for (int k=2;k<=npg;k<<=1){
    for (int j=k>>1;j>0;j>>=1){
      int ixj = tid ^ j;
      if (ixj > tid){
        float s1=ss[tid], s2=ss[ixj]; int i1=si[tid], i2=si[ixj];
        bool aAfterB = (s1 < s2) || (s1==s2 && i1 > i2);
        bool sw = ((tid & k)==0) ? aAfterB : !aAfterB;
        if (sw){ ss[tid]=s2; si[tid]=i2; ss[ixj]=s1; si[ixj]=i1; }
      }
      __syncthreads();
    }
  }
  if (tid < K){ perm[g*K+tid] = g*npg + si[tid]; vals[g*K+tid] = ss[tid]; }
}

__global__ void k_remap_set(const int* __restrict__ perm, int* __restrict__ remap, int n){
  int i = blockIdx.x*256+threadIdx.x; if (i<n) remap[perm[i]] = i;
}

// per-graph global max/mean pool over (1024,32), then MLP head + log_softmax
__global__ void k_head(const float* __restrict__ x13, const float* __restrict__ Wl,
                       const float* __restrict__ Wc, const float* __restrict__ bc,
                       float* __restrict__ out){
  __shared__ float smax[256], ssum[256];
  __shared__ float gv[64], g2[64], logit[10];
  int g = blockIdx.x, t = threadIdx.x;
  int f = t & 31, r0 = t >> 5;
  float mx = -3.4e38f, sm = 0.f;
  const float* base = x13 + (size_t)g*N_*32;
  for (int r=r0; r<N_; r+=8){ float v = base[r*32+f]; mx = fmaxf(mx,v); sm += v; }
  smax[t]=mx; ssum[t]=sm; __syncthreads();
  if (t<128){ smax[t]=fmaxf(smax[t],smax[t+128]); ssum[t]+=ssum[t+128]; } __syncthreads();
  if (t<64){ smax[t]=fmaxf(smax[t],smax[t+64]); ssum[t]+=ssum[t+64]; } __syncthreads();
  if (t<32){
    float m2 = fmaxf(smax[t],smax[t+32]); float s2 = ssum[t]+ssum[t+32];
    gv[t] = eluf(m2); gv[32+t] = eluf(s2 * (1.f/N_));
  }
  __syncthreads();
  if (t<64){
    float acc=0.f;
    #pragma unroll
    for (int i2=0;i2<64;++i2) acc = fmaf(gv[i2], Wl[i2*64+t], acc);
    g2[t] = eluf(acc);
  }
  __syncthreads();
  if (t<10){
    float acc = bc[t];
    #pragma unroll
    for (int j=0;j<64;++j) acc = fmaf(g2[j], Wc[j*10+t], acc);
    logit[t] = acc;
  }
  __syncthreads();
  if (t==0){
    float m=-3.4e38f; for (int c=0;c<10;++c) m=fmaxf(m,logit[c]);
    float s=0.f; for (int c=0;c<10;++c) s += expf(logit[c]-m);
    float lse = m + logf(s);
    for (int c=0;c<10;++c) out[g*10+c] = logit[c]-lse;
  }
}

extern "C" void kernel_launch(void* const* d_in, const int* in_sizes, int n_in,
                              void* d_out, int out_size, void* d_ws, size_t ws_size,
                              hipStream_t stream){
  const float* x  = (const float*)d_in[0];
  const float* W1 = (const float*)d_in[1];
  const float* b1 = (const float*)d_in[2];
  const float* p1 = (const float*)d_in[3];
  const float* W2 = (const float*)d_in[4];
  const float* b2 = (const float*)d_in[5];
  const float* p2 = (const float*)d_in[6];
  const float* W3 = (const float*)d_in[7];
  const float* b3 = (const float*)d_in[8];
  const float* p3 = (const float*)d_in[9];
  const float* W4 = (const float*)d_in[10];
  const float* b4 = (const float*)d_in[11];
  const float* W5 = (const float*)d_in[12];
  const float* b5 = (const float*)d_in[13];
  const float* W6 = (const float*)d_in[14];
  const float* b6 = (const float*)d_in[15];
  const float* W7 = (const float*)d_in[16];
  const float* b7 = (const float*)d_in[17];
  const float* Wl = (const float*)d_in[18];
  const float* Wc = (const float*)d_in[19];
  const float* bc = (const float*)d_in[20];
  const int* src0 = (const int*)d_in[21];
  const int* dst0 = (const int*)d_in[22];
  float* out = (float*)d_out;

  char* wsp = (char*)d_ws;
  size_t off = 0;
  auto alloc = [&](size_t bytes)->char*{
    char* p = wsp + off;
    off += (bytes + 255) & ~(size_t)255;
    return p;
  };
  float* bufA = (float*)alloc((size_t)2097152*4);   // x1 / x13
  float* bufB = (float*)alloc((size_t)2097152*4);   // x3
  float* bufC = (float*)alloc((size_t)2097152*4);   // x5 / x11
  float* bufD = (float*)alloc((size_t)2097152*4);   // x7 / x9
  float* bufH = (float*)alloc((size_t)2097152*4);   // pre-norm H
  float* score= (float*)alloc((size_t)M0_*4);
  float* vals2= (float*)alloc((size_t)M1_*4);
  float* vals4= (float*)alloc((size_t)M2_*4);
  float* vals6= (float*)alloc((size_t)M3_*4);
  int* idx2 = (int*)alloc((size_t)M1_*4);   // level2 -> level0
  int* idx4 = (int*)alloc((size_t)M2_*4);   // level4 -> level2
  int* idx6 = (int*)alloc((size_t)M3_*4);   // level6 -> level4
  int* orig4 = (int*)alloc((size_t)M2_*4);  // level4 -> level0
  int* orig6 = (int*)alloc((size_t)M3_*4);  // level6 -> level0
  int* rm02 = (int*)alloc((size_t)M0_*4);
  int* rm04 = (int*)alloc((size_t)M0_*4);
  int* rm06 = (int*)alloc((size_t)M0_*4);
  int* col0 = (int*)alloc((size_t)E_*4);
  int* rowptr0 = (int*)alloc((size_t)(M0_+1)*4);
  int* cursor0 = (int*)alloc((size_t)M0_*4);
  int* degi0 = (int*)alloc((size_t)M0_*4);
  int* bsum  = (int*)alloc((size_t)256*4);
  float* dinv0 = (float*)alloc((size_t)M0_*4);
  float* dinv2 = (float*)alloc((size_t)M1_*4);
  float* dinv4 = (float*)alloc((size_t)M2_*4);
  float* dinv6 = (float*)alloc((size_t)M3_*4);

  auto NB = [](int total){ return (total+255)/256; };

  // ---- level-0 CSR (shared by layers 1 and 7)
  hipMemsetAsync(degi0, 0, (size_t)M0_*4, stream);
  k_deg0<<<NB(E_),256,0,stream>>>(dst0, degi0);
  k_scanA<<<256,256,0,stream>>>(degi0, bsum);
  k_scanB<<<1,256,0,stream>>>(bsum);
  k_scanC<<<256,256,0,stream>>>(degi0, bsum, rowptr0, cursor0, dinv0);
  k_place0<<<NB(E_),256,0,stream>>>(src0, dst0, cursor0, col0);

  // ---- layer 1: gcn(x) -> x1 (bufA) + fused score1
  k_mm<128,32,0><<<dim3(M0_/128,1),256,0,stream>>>(x, W1, bufH, M0_, 128, 32,
      nullptr,nullptr,nullptr,nullptr,nullptr,0);
  k_gather<32,true><<<NB(M0_*8),256,0,stream>>>(rowptr0, col0, dinv0, bufH, b1, bufA, M0_, p1, score);

  // ---- pool 1
  k_topk<<<B_,1024,0,stream>>>(score, 1024, K1_, idx2, vals2);
  hipMemsetAsync(rm02, 0xFF, (size_t)M0_*4, stream);
  k_remap_set<<<NB(M1_),256,0,stream>>>(idx2, rm02, M1_);
  k_deg_orig<<<NB(M1_),256,0,stream>>>(idx2, rowptr0, col0, rm02, dinv2, M1_);

  // ---- layer 2 (X = fused pool of x1) -> x3 (bufB) + fused score2
  k_mm<64,64,1><<<dim3(M1_/64,1),256,0,stream>>>(bufA, W2, bufH, M1_, 32, 64,
      idx2, vals2, nullptr,nullptr,nullptr,0);
  k_gather_rm<64,true><<<NB(M1_*16),256,0,stream>>>(idx2, rowptr0, col0, rm02, dinv2, bufH, b2, bufB, M1_, p2, score);

  // ---- pool 2
  k_topk<<<B_,512,0,stream>>>(score, 512, K2_, idx4, vals4);
  k_compose_idx<<<NB(M2_),256,0,stream>>>(idx2, idx4, orig4, M2_);
  hipMemsetAsync(rm04, 0xFF, (size_t)M0_*4, stream);
  k_remap_set<<<NB(M2_),256,0,stream>>>(orig4, rm04, M2_);
  k_deg_orig<<<NB(M2_),256,0,stream>>>(orig4, rowptr0, col0, rm04, dinv4, M2_);

  // ---- layer 3 -> x5 (bufC) + fused score3
  k_mm<64,64,1><<<dim3(M2_/64,2),256,0,stream>>>(bufB, W3, bufH, M2_, 64, 128,
      idx4, vals4, nullptr,nullptr,nullptr,0);
  k_gather_rm<128,true><<<NB(M2_*32),256,0,stream>>>(orig4, rowptr0, col0, rm04, dinv4, bufH, b3, bufC, M2_, p3, score);

  // ---- pool 3
  k_topk<<<B_,256,0,stream>>>(score, 256, K3_, idx6, vals6);
  k_compose_idx<<<NB(M3_),256,0,stream>>>(orig4, idx6, orig6, M3_);
  hipMemsetAsync(rm06, 0xFF, (size_t)M0_*4, stream);
  k_remap_set<<<NB(M3_),256,0,stream>>>(orig6, rm06, M3_);
  k_deg_orig<<<NB(M3_),256,0,stream>>>(orig6, rowptr0, col0, rm06, dinv6, M3_);

  // ---- layer 4 -> x7 (bufD)
  k_mm<64,64,1><<<dim3(M3_/64,4),256,0,stream>>>(bufC, W4, bufH, M3_, 128, 256,
      idx6, vals6, nullptr,nullptr,nullptr,0);
  k_gather_rm<256,false><<<NB(M3_*64),256,0,stream>>>(orig6, rowptr0, col0, rm06, dinv6, bufH, b4, bufD, M3_, nullptr, nullptr);

  // ---- layer 5 (X = fused concat(x7 scattered, x5)) -> x9 (bufD)
  k_mm<64,64,2><<<dim3(M2_/64,2),256,0,stream>>>(bufC, W5, bufH, M2_, 384, 128,
      nullptr,nullptr, bufD, orig4, rm06, 64);
  k_gather_rm<128,false><<<NB(M2_*32),256,0,stream>>>(orig4, rowptr0, col0, rm04, dinv4, bufH, b5, bufD, M2_, nullptr, nullptr);

  // ---- layer 6 (X = fused concat(x9 scattered, x3)) -> x11 (bufC)
  k_mm<64,64,2><<<dim3(M1_/64,1),256,0,stream>>>(bufB, W6, bufH, M1_, 192, 64,
      nullptr,nullptr, bufD, idx2, rm04, 32);
  k_gather_rm<64,false><<<NB(M1_*16),256,0,stream>>>(idx2, rowptr0, col0, rm02, dinv2, bufH, b6, bufC, M1_, nullptr, nullptr);

  // ---- layer 7 (X = fused concat(x11 scattered, x1)) -> x13 (bufA)
  k_mm<128,32,2><<<dim3(M0_/128,1),256,0,stream>>>(bufA, W7, bufH, M0_, 96, 32,
      nullptr,nullptr, bufC, nullptr, rm02, 16);
  k_gather<32,false><<<NB(M0_*8),256,0,stream>>>(rowptr0, col0, dinv0, bufH, b7, bufA, M0_, nullptr, nullptr);

  // ---- head
  k_head<<<B_,256,0,stream>>>(bufA, Wl, Wc, bc, out);

  (void)in_sizes; (void)n_in; (void)out_size; (void)ws_size;
}

// Round 9
// 403.863 us; speedup vs baseline: 1.1659x; 1.1659x over previous
//
#include <hip/hip_runtime.h>
#include <hip/hip_bf16.h>
#include <math.h>

#define B_ 64
#define N_ 1024
#define E_ 524288
#define K1_ 512
#define K2_ 256
#define K3_ 128
#define M0_ 65536
#define M1_ 32768
#define M2_ 16384
#define M3_ 8192

static __device__ __forceinline__ float eluf(float x){ return x > 0.f ? x : expm1f(x); }
static __device__ __forceinline__ float4 elu4(float4 v){
  float4 o; o.x=eluf(v.x); o.y=eluf(v.y); o.z=eluf(v.z); o.w=eluf(v.w); return o;
}

// Tiled GEMM, BM x BN block, 256 threads, round-6 schedule (simple 2-barrier
// loop; pipelining attempts regressed twice). Inner loop processes 4 kk per
// group with float4 reads of BOTH fragments: 2 LDS instr/kk instead of 5
// (round-6 was LDS-issue bound at 40% VALUBusy). RM = 4 always.
// MODE 0: H = X @ W
// MODE 1: H = elu(X[perm[m]]*vals[m]) @ W        (fused top-k pool gather)
// MODE 2: H = elu(concat(Xd via rm/orig, Xs)) @ W (fused unpool+concat)
template<int BM,int BN,int MODE>
__global__ __launch_bounds__(256) void k_mm(const float* __restrict__ X,
    const float* __restrict__ W, float* __restrict__ H, int M, int K, int N,
    const int* __restrict__ perm, const float* __restrict__ vals,
    const float* __restrict__ Xd, const int* __restrict__ orig,
    const int* __restrict__ rm, int WD4){
  constexpr int TX = BN/4;
  constexpr int TY = 256/TX;
  constexpr int RM = BM/TY;          // = 4
  __shared__ float Xs[BM][36];       // pad 36: rows 144B (16B-aligned), 2-way max
  __shared__ float Ws[32][BN];
  const int t = threadIdx.x;
  const int tx = t % TX, ty = t / TX;
  const int m0 = blockIdx.x*BM, n0 = blockIdx.y*BN;
  float acc[RM][4];
  #pragma unroll
  for (int r=0;r<RM;++r){acc[r][0]=0.f;acc[r][1]=0.f;acc[r][2]=0.f;acc[r][3]=0.f;}
  for (int k0=0;k0<K;k0+=32){
    #pragma unroll
    for (int l=0;l<BM/32;++l){           // X tile: BM*8 float4s
      int fi=l*256+t, row=fi>>3, q=fi&7;
      int m = m0+row;
      int c4 = (k0>>2)+q;
      float4 v;
      if (MODE==0){
        v = *(const float4*)(X + (size_t)m*K + (c4<<2));
      } else if (MODE==1){
        int pm = perm[m]; float vv = vals[m];
        float4 h = *(const float4*)(X + (size_t)pm*K + (c4<<2));
        v.x=eluf(h.x*vv); v.y=eluf(h.y*vv); v.z=eluf(h.z*vv); v.w=eluf(h.w*vv);
      } else {
        if (c4 < WD4){
          int o = orig ? orig[m] : m;
          int j = rm[o];
          if (j>=0) v = elu4(*(const float4*)(Xd + ((size_t)j*WD4 + c4)*4));
          else { v.x=0.f;v.y=0.f;v.z=0.f;v.w=0.f; }
        } else {
          int ws4 = (K>>2) - WD4;
          v = elu4(*(const float4*)(X + ((size_t)m*ws4 + (c4-WD4))*4));
        }
      }
      *(float4*)(&Xs[row][q*4]) = v;
    }
    #pragma unroll
    for (int l=0;l<BN/32;++l){           // W tile: 8*BN float4s
      int fi=l*256+t, wrow=fi/(BN/4), wq=fi%(BN/4);
      *(float4*)(&Ws[wrow][wq*4]) = *(const float4*)(W + (size_t)(k0+wrow)*N + n0 + wq*4);
    }
    __syncthreads();
    #pragma unroll
    for (int kq=0;kq<32;kq+=4){
      float4 xv[RM];
      #pragma unroll
      for (int r=0;r<RM;++r) xv[r] = *(const float4*)(&Xs[ty*RM+r][kq]);
      #pragma unroll
      for (int j=0;j<4;++j){
        float4 wv = *(const float4*)(&Ws[kq+j][tx*4]);
        #pragma unroll
        for (int r=0;r<RM;++r){
          float xs = (j==0)?xv[r].x:(j==1)?xv[r].y:(j==2)?xv[r].z:xv[r].w;
          acc[r][0]=fmaf(xs,wv.x,acc[r][0]);
          acc[r][1]=fmaf(xs,wv.y,acc[r][1]);
          acc[r][2]=fmaf(xs,wv.z,acc[r][2]);
          acc[r][3]=fmaf(xs,wv.w,acc[r][3]);
        }
      }
    }
    __syncthreads();
  }
  #pragma unroll
  for (int r=0;r<RM;++r){
    int m = m0 + ty*RM + r;
    float4 h; h.x=acc[r][0];h.y=acc[r][1];h.z=acc[r][2];h.w=acc[r][3];
    *(float4*)(H + (size_t)m*N + n0 + tx*4) = h;
  }
}

// ---- level-0 CSR build (spread atomics only) ----
__global__ void k_deg0(const int* __restrict__ dst, int* __restrict__ degi){
  int i = blockIdx.x*256+threadIdx.x; if (i>=E_) return;
  atomicAdd(&degi[dst[i]], 1);
}
__global__ void k_place0(const int* __restrict__ src, const int* __restrict__ dst,
                         int* __restrict__ cursor, int* __restrict__ col){
  int i = blockIdx.x*256+threadIdx.x; if (i>=E_) return;
  int p = atomicAdd(&cursor[dst[i]], 1);
  col[p] = src[i];
}

// ---- hierarchical scan over M0 degrees ----
__global__ __launch_bounds__(256) void k_scanA(const int* __restrict__ degi,
                                               int* __restrict__ bsum){
  __shared__ int ls[256];
  int b = blockIdx.x, t = threadIdx.x;
  ls[t] = degi[b*256+t]; __syncthreads();
  for (int o=128;o>0;o>>=1){ if (t<o) ls[t]+=ls[t+o]; __syncthreads(); }
  if (t==0) bsum[b] = ls[0];
}
__global__ __launch_bounds__(256) void k_scanB(int* __restrict__ bsum){
  __shared__ int ps[256];
  int t = threadIdx.x;
  ps[t] = bsum[t]; __syncthreads();
  for (int o=1;o<256;o<<=1){
    int v = (t>=o) ? ps[t-o] : 0;
    __syncthreads(); ps[t]+=v; __syncthreads();
  }
  bsum[t] = ps[t];
}
__global__ __launch_bounds__(256) void k_scanC(const int* __restrict__ degi,
    const int* __restrict__ bsum, int* __restrict__ rowptr,
    int* __restrict__ cursor, float* __restrict__ dinv){
  __shared__ int ps[256];
  int b = blockIdx.x, t = threadIdx.x;
  int i = b*256+t;
  int d = degi[i];
  ps[t] = d; __syncthreads();
  for (int o=1;o<256;o<<=1){
    int v = (t>=o) ? ps[t-o] : 0;
    __syncthreads(); ps[t]+=v; __syncthreads();
  }
  int off = (b==0 ? 0 : bsum[b-1]) + ps[t] - d;
  rowptr[i] = off; cursor[i] = off;
  dinv[i] = rsqrtf((float)d + 2.f);
  if (i == M0_-1) rowptr[M0_] = off + d;
}

// pooled-level degree via rm-filtered level-0 CSR
__global__ void k_deg_orig(const int* __restrict__ orig, const int* __restrict__ rowptr0,
                           const int* __restrict__ col0, const int* __restrict__ rm,
                           float* __restrict__ dinv, int M){
  int i = blockIdx.x*256+threadIdx.x; if (i>=M) return;
  int o = orig[i];
  int beg = rowptr0[o], end = rowptr0[o+1];
  int d = 0;
  for (int j=beg;j<end;++j) d += (rm[col0[j]] >= 0) ? 1 : 0;
  dinv[i] = rsqrtf((float)d + 2.f);
}

__global__ void k_compose_idx(const int* __restrict__ prevOrig, const int* __restrict__ idxL,
                              int* __restrict__ origL, int n){
  int i = blockIdx.x*256+threadIdx.x; if (i<n) origL[i] = prevOrig[idxL[i]];
}

// ---- level-0 GCN aggregation; optional fused pool-score output
template<int F, bool SCORE>
__global__ __launch_bounds__(256) void k_gather(const int* __restrict__ rowptr,
    const int* __restrict__ col, const float* __restrict__ dinv,
    const float* __restrict__ H, const float* __restrict__ bias,
    float* __restrict__ OUT, int M,
    const float* __restrict__ p, float* __restrict__ score){
  constexpr int FQ = F/4;
  int i = blockIdx.x*256+threadIdx.x;
  if (i >= M*FQ) return;
  int n = i/FQ, q = i - (i/FQ)*FQ;
  int beg = rowptr[n], end = rowptr[n+1];
  float4 acc; acc.x=0.f;acc.y=0.f;acc.z=0.f;acc.w=0.f;
  for (int j=beg;j<end;++j){
    int s = col[j];
    float c = dinv[s];
    float4 h = *(const float4*)(H + (size_t)s*F + q*4);
    acc.x=fmaf(c,h.x,acc.x); acc.y=fmaf(c,h.y,acc.y);
    acc.z=fmaf(c,h.z,acc.z); acc.w=fmaf(c,h.w,acc.w);
  }
  float dn = dinv[n];
  float sc = 2.f*dn*dn;
  float4 hn = *(const float4*)(H + (size_t)n*F + q*4);
  float4 bv = *(const float4*)(bias + q*4);
  float4 o;
  o.x = eluf(fmaf(sc,hn.x,fmaf(dn,acc.x,bv.x)));
  o.y = eluf(fmaf(sc,hn.y,fmaf(dn,acc.y,bv.y)));
  o.z = eluf(fmaf(sc,hn.z,fmaf(dn,acc.z,bv.z)));
  o.w = eluf(fmaf(sc,hn.w,fmaf(dn,acc.w,bv.w)));
  *(float4*)(OUT + (size_t)n*F + q*4) = o;
  if (SCORE){
    float4 pv = *(const float4*)(p + q*4);
    float dot = o.x*pv.x + o.y*pv.y + o.z*pv.z + o.w*pv.w;
    float n2  = pv.x*pv.x + pv.y*pv.y + pv.z*pv.z + pv.w*pv.w;
    #pragma unroll
    for (int mk=FQ>>1; mk>0; mk>>=1){
      dot += __shfl_xor(dot, mk);
      n2  += __shfl_xor(n2,  mk);
    }
    if (q==0) score[n] = tanhf(dot * rsqrtf(n2));
  }
}

// ---- pooled-level GCN aggregation through rm filter; optional fused score
template<int F, bool SCORE>
__global__ __launch_bounds__(256) void k_gather_rm(const int* __restrict__ orig,
    const int* __restrict__ rowptr0, const int* __restrict__ col0,
    const int* __restrict__ rm, const float* __restrict__ dinv,
    const float* __restrict__ H, const float* __restrict__ bias,
    float* __restrict__ OUT, int M,
    const float* __restrict__ p, float* __restrict__ score){
  constexpr int FQ = F/4;
  int i = blockIdx.x*256+threadIdx.x;
  if (i >= M*FQ) return;
  int n = i/FQ, q = i - (i/FQ)*FQ;
  int o = orig[n];
  int beg = rowptr0[o], end = rowptr0[o+1];
  float4 acc; acc.x=0.f;acc.y=0.f;acc.z=0.f;acc.w=0.f;
  for (int j=beg;j<end;++j){
    int s = rm[col0[j]];
    if (s >= 0){
      float c = dinv[s];
      float4 h = *(const float4*)(H + (size_t)s*F + q*4);
      acc.x=fmaf(c,h.x,acc.x); acc.y=fmaf(c,h.y,acc.y);
      acc.z=fmaf(c,h.z,acc.z); acc.w=fmaf(c,h.w,acc.w);
    }
  }
  float dn = dinv[n];
  float sc = 2.f*dn*dn;
  float4 hn = *(const float4*)(H + (size_t)n*F + q*4);
  float4 bv = *(const float4*)(bias + q*4);
  float4 ov;
  ov.x = eluf(fmaf(sc,hn.x,fmaf(dn,acc.x,bv.x)));
  ov.y = eluf(fmaf(sc,hn.y,fmaf(dn,acc.y,bv.y)));
  ov.z = eluf(fmaf(sc,hn.z,fmaf(dn,acc.z,bv.z)));
  ov.w = eluf(fmaf(sc,hn.w,fmaf(dn,acc.w,bv.w)));
  *(float4*)(OUT + (size_t)n*F + q*4) = ov;
  if (SCORE){
    float4 pv = *(const float4*)(p + q*4);
    float dot = ov.x*pv.x + ov.y*pv.y + ov.z*pv.z + ov.w*pv.w;
    float n2  = pv.x*pv.x + pv.y*pv.y + pv.z*pv.z + pv.w*pv.w;
    #pragma unroll
    for (int mk=FQ>>1; mk>0; mk>>=1){
      dot += __shfl_xor(dot, mk);
      n2  += __shfl_xor(n2,  mk);
    }
    if (q==0) score[n] = tanhf(dot * rsqrtf(n2));
  }
}

// block g sorts its npg scores descending (tie: lower index first), writes top-K
__global__ void k_topk(const float* __restrict__ score, int npg, int K,
                       int* __restrict__ perm, float* __restrict__ vals){
  __shared__ float ss[1024]; __shared__ int si[1024];
  int g = blockIdx.x, tid = threadIdx.x;
  ss[tid] = score[g*npg + tid]; si[tid] = tid;
  __syncthreads();
  for (int k=2;k<=npg;k<<=1){
    for (int j=k>>1;j>0;j>>=1){
      int ixj = tid ^ j;
      if (ixj > tid){
        float s1=ss[tid], s2=ss[ixj]; int i1=si[tid], i2=si[ixj];
        bool aAfterB = (s1 < s2) || (s1==s2 && i1 > i2);
        bool sw = ((tid & k)==0) ? aAfterB : !aAfterB;
        if (sw){ ss[tid]=s2; si[tid]=i2; ss[ixj]=s1; si[ixj]=i1; }
      }
      __syncthreads();
    }
  }
  if (tid < K){ perm[g*K+tid] = g*npg + si[tid]; vals[g*K+tid] = ss[tid]; }
}

__global__ void k_remap_set(const int* __restrict__ perm, int* __restrict__ remap, int n){
  int i = blockIdx.x*256+threadIdx.x; if (i<n) remap[perm[i]] = i;
}

// per-graph global max/mean pool over (1024,32), then MLP head + log_softmax
__global__ void k_head(const float* __restrict__ x13, const float* __restrict__ Wl,
                       const float* __restrict__ Wc, const float* __restrict__ bc,
                       float* __restrict__ out){
  __shared__ float smax[256], ssum[256];
  __shared__ float gv[64], g2[64], logit[10];
  int g = blockIdx.x, t = threadIdx.x;
  int f = t & 31, r0 = t >> 5;
  float mx = -3.4e38f, sm = 0.f;
  const float* base = x13 + (size_t)g*N_*32;
  for (int r=r0; r<N_; r+=8){ float v = base[r*32+f]; mx = fmaxf(mx,v); sm += v; }
  smax[t]=mx; ssum[t]=sm; __syncthreads();
  if (t<128){ smax[t]=fmaxf(smax[t],smax[t+128]); ssum[t]+=ssum[t+128]; } __syncthreads();
  if (t<64){ smax[t]=fmaxf(smax[t],smax[t+64]); ssum[t]+=ssum[t+64]; } __syncthreads();
  if (t<32){
    float m2 = fmaxf(smax[t],smax[t+32]); float s2 = ssum[t]+ssum[t+32];
    gv[t] = eluf(m2); gv[32+t] = eluf(s2 * (1.f/N_));
  }
  __syncthreads();
  if (t<64){
    float acc=0.f;
    #pragma unroll
    for (int i2=0;i2<64;++i2) acc = fmaf(gv[i2], Wl[i2*64+t], acc);
    g2[t] = eluf(acc);
  }
  __syncthreads();
  if (t<10){
    float acc = bc[t];
    #pragma unroll
    for (int j=0;j<64;++j) acc = fmaf(g2[j], Wc[j*10+t], acc);
    logit[t] = acc;
  }
  __syncthreads();
  if (t==0){
    float m=-3.4e38f; for (int c=0;c<10;++c) m=fmaxf(m,logit[c]);
    float s=0.f; for (int c=0;c<10;++c) s += expf(logit[c]-m);
    float lse = m + logf(s);
    for (int c=0;c<10;++c) out[g*10+c] = logit[c]-lse;
  }
}

extern "C" void kernel_launch(void* const* d_in, const int* in_sizes, int n_in,
                              void* d_out, int out_size, void* d_ws, size_t ws_size,
                              hipStream_t stream){
  const float* x  = (const float*)d_in[0];
  const float* W1 = (const float*)d_in[1];
  const float* b1 = (const float*)d_in[2];
  const float* p1 = (const float*)d_in[3];
  const float* W2 = (const float*)d_in[4];
  const float* b2 = (const float*)d_in[5];
  const float* p2 = (const float*)d_in[6];
  const float* W3 = (const float*)d_in[7];
  const float* b3 = (const float*)d_in[8];
  const float* p3 = (const float*)d_in[9];
  const float* W4 = (const float*)d_in[10];
  const float* b4 = (const float*)d_in[11];
  const float* W5 = (const float*)d_in[12];
  const float* b5 = (const float*)d_in[13];
  const float* W6 = (const float*)d_in[14];
  const float* b6 = (const float*)d_in[15];
  const float* W7 = (const float*)d_in[16];
  const float* b7 = (const float*)d_in[17];
  const float* Wl = (const float*)d_in[18];
  const float* Wc = (const float*)d_in[19];
  const float* bc = (const float*)d_in[20];
  const int* src0 = (const int*)d_in[21];
  const int* dst0 = (const int*)d_in[22];
  float* out = (float*)d_out;

  char* wsp = (char*)d_ws;
  size_t off = 0;
  auto alloc = [&](size_t bytes)->char*{
    char* p = wsp + off;
    off += (bytes + 255) & ~(size_t)255;
    return p;
  };
  float* bufA = (float*)alloc((size_t)2097152*4);   // x1 / x13
  float* bufB = (float*)alloc((size_t)2097152*4);   // x3
  float* bufC = (float*)alloc((size_t)2097152*4);   // x5 / x11
  float* bufD = (float*)alloc((size_t)2097152*4);   // x7 / x9
  float* bufH = (float*)alloc((size_t)2097152*4);   // pre-norm H
  float* score= (float*)alloc((size_t)M0_*4);
  float* vals2= (float*)alloc((size_t)M1_*4);
  float* vals4= (float*)alloc((size_t)M2_*4);
  float* vals6= (float*)alloc((size_t)M3_*4);
  int* idx2 = (int*)alloc((size_t)M1_*4);   // level2 -> level0
  int* idx4 = (int*)alloc((size_t)M2_*4);   // level4 -> level2
  int* idx6 = (int*)alloc((size_t)M3_*4);   // level6 -> level4
  int* orig4 = (int*)alloc((size_t)M2_*4);  // level4 -> level0
  int* orig6 = (int*)alloc((size_t)M3_*4);  // level6 -> level0
  int* rm02 = (int*)alloc((size_t)M0_*4);
  int* rm04 = (int*)alloc((size_t)M0_*4);
  int* rm06 = (int*)alloc((size_t)M0_*4);
  int* col0 = (int*)alloc((size_t)E_*4);
  int* rowptr0 = (int*)alloc((size_t)(M0_+1)*4);
  int* cursor0 = (int*)alloc((size_t)M0_*4);
  int* degi0 = (int*)alloc((size_t)M0_*4);
  int* bsum  = (int*)alloc((size_t)256*4);
  float* dinv0 = (float*)alloc((size_t)M0_*4);
  float* dinv2 = (float*)alloc((size_t)M1_*4);
  float* dinv4 = (float*)alloc((size_t)M2_*4);
  float* dinv6 = (float*)alloc((size_t)M3_*4);

  auto NB = [](int total){ return (total+255)/256; };

  // ---- level-0 CSR (shared by layers 1 and 7)
  hipMemsetAsync(degi0, 0, (size_t)M0_*4, stream);
  k_deg0<<<NB(E_),256,0,stream>>>(dst0, degi0);
  k_scanA<<<256,256,0,stream>>>(degi0, bsum);
  k_scanB<<<1,256,0,stream>>>(bsum);
  k_scanC<<<256,256,0,stream>>>(degi0, bsum, rowptr0, cursor0, dinv0);
  k_place0<<<NB(E_),256,0,stream>>>(src0, dst0, cursor0, col0);

  // ---- layer 1: gcn(x) -> x1 (bufA) + fused score1
  k_mm<128,32,0><<<dim3(M0_/128,1),256,0,stream>>>(x, W1, bufH, M0_, 128, 32,
      nullptr,nullptr,nullptr,nullptr,nullptr,0);
  k_gather<32,true><<<NB(M0_*8),256,0,stream>>>(rowptr0, col0, dinv0, bufH, b1, bufA, M0_, p1, score);

  // ---- pool 1
  k_topk<<<B_,1024,0,stream>>>(score, 1024, K1_, idx2, vals2);
  hipMemsetAsync(rm02, 0xFF, (size_t)M0_*4, stream);
  k_remap_set<<<NB(M1_),256,0,stream>>>(idx2, rm02, M1_);
  k_deg_orig<<<NB(M1_),256,0,stream>>>(idx2, rowptr0, col0, rm02, dinv2, M1_);

  // ---- layer 2 (X = fused pool of x1) -> x3 (bufB) + fused score2
  k_mm<64,64,1><<<dim3(M1_/64,1),256,0,stream>>>(bufA, W2, bufH, M1_, 32, 64,
      idx2, vals2, nullptr,nullptr,nullptr,0);
  k_gather_rm<64,true><<<NB(M1_*16),256,0,stream>>>(idx2, rowptr0, col0, rm02, dinv2, bufH, b2, bufB, M1_, p2, score);

  // ---- pool 2
  k_topk<<<B_,512,0,stream>>>(score, 512, K2_, idx4, vals4);
  k_compose_idx<<<NB(M2_),256,0,stream>>>(idx2, idx4, orig4, M2_);
  hipMemsetAsync(rm04, 0xFF, (size_t)M0_*4, stream);
  k_remap_set<<<NB(M2_),256,0,stream>>>(orig4, rm04, M2_);
  k_deg_orig<<<NB(M2_),256,0,stream>>>(orig4, rowptr0, col0, rm04, dinv4, M2_);

  // ---- layer 3 -> x5 (bufC) + fused score3
  k_mm<64,64,1><<<dim3(M2_/64,2),256,0,stream>>>(bufB, W3, bufH, M2_, 64, 128,
      idx4, vals4, nullptr,nullptr,nullptr,0);
  k_gather_rm<128,true><<<NB(M2_*32),256,0,stream>>>(orig4, rowptr0, col0, rm04, dinv4, bufH, b3, bufC, M2_, p3, score);

  // ---- pool 3
  k_topk<<<B_,256,0,stream>>>(score, 256, K3_, idx6, vals6);
  k_compose_idx<<<NB(M3_),256,0,stream>>>(orig4, idx6, orig6, M3_);
  hipMemsetAsync(rm06, 0xFF, (size_t)M0_*4, stream);
  k_remap_set<<<NB(M3_),256,0,stream>>>(orig6, rm06, M3_);
  k_deg_orig<<<NB(M3_),256,0,stream>>>(orig6, rowptr0, col0, rm06, dinv6, M3_);

  // ---- layer 4 -> x7 (bufD)
  k_mm<64,64,1><<<dim3(M3_/64,4),256,0,stream>>>(bufC, W4, bufH, M3_, 128, 256,
      idx6, vals6, nullptr,nullptr,nullptr,0);
  k_gather_rm<256,false><<<NB(M3_*64),256,0,stream>>>(orig6, rowptr0, col0, rm06, dinv6, bufH, b4, bufD, M3_, nullptr, nullptr);

  // ---- layer 5 (X = fused concat(x7 scattered, x5)) -> x9 (bufD)
  k_mm<64,64,2><<<dim3(M2_/64,2),256,0,stream>>>(bufC, W5, bufH, M2_, 384, 128,
      nullptr,nullptr, bufD, orig4, rm06, 64);
  k_gather_rm<128,false><<<NB(M2_*32),256,0,stream>>>(orig4, rowptr0, col0, rm04, dinv4, bufH, b5, bufD, M2_, nullptr, nullptr);

  // ---- layer 6 (X = fused concat(x9 scattered, x3)) -> x11 (bufC)
  k_mm<64,64,2><<<dim3(M1_/64,1),256,0,stream>>>(bufB, W6, bufH, M1_, 192, 64,
      nullptr,nullptr, bufD, idx2, rm04, 32);
  k_gather_rm<64,false><<<NB(M1_*16),256,0,stream>>>(idx2, rowptr0, col0, rm02, dinv2, bufH, b6, bufC, M1_, nullptr, nullptr);

  // ---- layer 7 (X = fused concat(x11 scattered, x1)) -> x13 (bufA)
  k_mm<128,32,2><<<dim3(M0_/128,1),256,0,stream>>>(bufA, W7, bufH, M0_, 96, 32,
      nullptr,nullptr, bufC, nullptr, rm02, 16);
  k_gather<32,false><<<NB(M0_*8),256,0,stream>>>(rowptr0, col0, dinv0, bufH, b7, bufA, M0_, nullptr, nullptr);

  // ---- head
  k_head<<<B_,256,0,stream>>>(bufA, Wl, Wc, bc, out);

  (void)in_sizes; (void)n_in; (void)out_size; (void)ws_size;
}

// Round 10
// 401.440 us; speedup vs baseline: 1.1730x; 1.0060x over previous
//
#include <hip/hip_runtime.h>
#include <hip/hip_bf16.h>
#include <math.h>

#define B_ 64
#define N_ 1024
#define E_ 524288
#define K1_ 512
#define K2_ 256
#define K3_ 128
#define M0_ 65536
#define M1_ 32768
#define M2_ 16384
#define M3_ 8192

static __device__ __forceinline__ float eluf(float x){ return x > 0.f ? x : expm1f(x); }
static __device__ __forceinline__ float4 elu4(float4 v){
  float4 o; o.x=eluf(v.x); o.y=eluf(v.y); o.z=eluf(v.z); o.w=eluf(v.w); return o;
}

// Tiled GEMM, 64x32 tile, 256 threads (TX=8,TY=32,RM=2), simple 2-barrier loop.
// Tile sized so EVERY layer launches 1024 blocks = 4 independent blocks/CU
// (round-6/9 profile: 2 blocks/CU grid-limited, 60% staging stall in lockstep).
// MODE 0: H = X @ W
// MODE 1: H = elu(X[perm[m]]*vals[m]) @ W        (fused top-k pool gather)
// MODE 2: H = elu(concat(Xd via rm/orig, Xs)) @ W (fused unpool+concat)
template<int BM,int BN,int MODE>
__global__ __launch_bounds__(256) void k_mm(const float* __restrict__ X,
    const float* __restrict__ W, float* __restrict__ H, int M, int K, int N,
    const int* __restrict__ perm, const float* __restrict__ vals,
    const float* __restrict__ Xd, const int* __restrict__ orig,
    const int* __restrict__ rm, int WD4){
  constexpr int TX = BN/4;
  constexpr int TY = 256/TX;
  constexpr int RM = BM/TY;
  __shared__ float Xs[BM][36];       // rows 144B: 16B-aligned, 2-way max (free)
  __shared__ float Ws[32][BN];
  const int t = threadIdx.x;
  const int tx = t % TX, ty = t / TX;
  const int m0 = blockIdx.x*BM, n0 = blockIdx.y*BN;
  float acc[RM][4];
  #pragma unroll
  for (int r=0;r<RM;++r){acc[r][0]=0.f;acc[r][1]=0.f;acc[r][2]=0.f;acc[r][3]=0.f;}
  for (int k0=0;k0<K;k0+=32){
    #pragma unroll
    for (int l=0;l<BM/32;++l){           // X tile: BM*8 float4s
      int fi=l*256+t, row=fi>>3, q=fi&7;
      int m = m0+row;
      int c4 = (k0>>2)+q;
      float4 v;
      if (MODE==0){
        v = *(const float4*)(X + (size_t)m*K + (c4<<2));
      } else if (MODE==1){
        int pm = perm[m]; float vv = vals[m];
        float4 h = *(const float4*)(X + (size_t)pm*K + (c4<<2));
        v.x=eluf(h.x*vv); v.y=eluf(h.y*vv); v.z=eluf(h.z*vv); v.w=eluf(h.w*vv);
      } else {
        if (c4 < WD4){
          int o = orig ? orig[m] : m;
          int j = rm[o];
          if (j>=0) v = elu4(*(const float4*)(Xd + ((size_t)j*WD4 + c4)*4));
          else { v.x=0.f;v.y=0.f;v.z=0.f;v.w=0.f; }
        } else {
          int ws4 = (K>>2) - WD4;
          v = elu4(*(const float4*)(X + ((size_t)m*ws4 + (c4-WD4))*4));
        }
      }
      *(float4*)(&Xs[row][q*4]) = v;
    }
    #pragma unroll
    for (int l=0;l<BN/32;++l){           // W tile: 8*BN float4s
      int fi=l*256+t, wrow=fi/(BN/4), wq=fi%(BN/4);
      *(float4*)(&Ws[wrow][wq*4]) = *(const float4*)(W + (size_t)(k0+wrow)*N + n0 + wq*4);
    }
    __syncthreads();
    #pragma unroll
    for (int kq=0;kq<32;kq+=4){
      float4 xv[RM];
      #pragma unroll
      for (int r=0;r<RM;++r) xv[r] = *(const float4*)(&Xs[ty*RM+r][kq]);
      #pragma unroll
      for (int j=0;j<4;++j){
        float4 wv = *(const float4*)(&Ws[kq+j][tx*4]);
        #pragma unroll
        for (int r=0;r<RM;++r){
          float xs = (j==0)?xv[r].x:(j==1)?xv[r].y:(j==2)?xv[r].z:xv[r].w;
          acc[r][0]=fmaf(xs,wv.x,acc[r][0]);
          acc[r][1]=fmaf(xs,wv.y,acc[r][1]);
          acc[r][2]=fmaf(xs,wv.z,acc[r][2]);
          acc[r][3]=fmaf(xs,wv.w,acc[r][3]);
        }
      }
    }
    __syncthreads();
  }
  #pragma unroll
  for (int r=0;r<RM;++r){
    int m = m0 + ty*RM + r;
    float4 h; h.x=acc[r][0];h.y=acc[r][1];h.z=acc[r][2];h.w=acc[r][3];
    *(float4*)(H + (size_t)m*N + n0 + tx*4) = h;
  }
}

// ---- level-0 CSR build (spread atomics only) ----
__global__ void k_deg0(const int* __restrict__ dst, int* __restrict__ degi){
  int i = blockIdx.x*256+threadIdx.x; if (i>=E_) return;
  atomicAdd(&degi[dst[i]], 1);
}
__global__ void k_place0(const int* __restrict__ src, const int* __restrict__ dst,
                         int* __restrict__ cursor, int* __restrict__ col){
  int i = blockIdx.x*256+threadIdx.x; if (i>=E_) return;
  int p = atomicAdd(&cursor[dst[i]], 1);
  col[p] = src[i];
}

// ---- hierarchical scan over M0 degrees ----
__global__ __launch_bounds__(256) void k_scanA(const int* __restrict__ degi,
                                               int* __restrict__ bsum){
  __shared__ int ls[256];
  int b = blockIdx.x, t = threadIdx.x;
  ls[t] = degi[b*256+t]; __syncthreads();
  for (int o=128;o>0;o>>=1){ if (t<o) ls[t]+=ls[t+o]; __syncthreads(); }
  if (t==0) bsum[b] = ls[0];
}
__global__ __launch_bounds__(256) void k_scanB(int* __restrict__ bsum){
  __shared__ int ps[256];
  int t = threadIdx.x;
  ps[t] = bsum[t]; __syncthreads();
  for (int o=1;o<256;o<<=1){
    int v = (t>=o) ? ps[t-o] : 0;
    __syncthreads(); ps[t]+=v; __syncthreads();
  }
  bsum[t] = ps[t];
}
__global__ __launch_bounds__(256) void k_scanC(const int* __restrict__ degi,
    const int* __restrict__ bsum, int* __restrict__ rowptr,
    int* __restrict__ cursor, float* __restrict__ dinv){
  __shared__ int ps[256];
  int b = blockIdx.x, t = threadIdx.x;
  int i = b*256+t;
  int d = degi[i];
  ps[t] = d; __syncthreads();
  for (int o=1;o<256;o<<=1){
    int v = (t>=o) ? ps[t-o] : 0;
    __syncthreads(); ps[t]+=v; __syncthreads();
  }
  int off = (b==0 ? 0 : bsum[b-1]) + ps[t] - d;
  rowptr[i] = off; cursor[i] = off;
  dinv[i] = rsqrtf((float)d + 2.f);
  if (i == M0_-1) rowptr[M0_] = off + d;
}

// pooled-level degree via rm-filtered level-0 CSR
__global__ void k_deg_orig(const int* __restrict__ orig, const int* __restrict__ rowptr0,
                           const int* __restrict__ col0, const int* __restrict__ rm,
                           float* __restrict__ dinv, int M){
  int i = blockIdx.x*256+threadIdx.x; if (i>=M) return;
  int o = orig[i];
  int beg = rowptr0[o], end = rowptr0[o+1];
  int d = 0;
  for (int j=beg;j<end;++j) d += (rm[col0[j]] >= 0) ? 1 : 0;
  dinv[i] = rsqrtf((float)d + 2.f);
}

__global__ void k_compose_idx(const int* __restrict__ prevOrig, const int* __restrict__ idxL,
                              int* __restrict__ origL, int n){
  int i = blockIdx.x*256+threadIdx.x; if (i<n) origL[i] = prevOrig[idxL[i]];
}

// ---- level-0 GCN aggregation; optional fused pool-score output
template<int F, bool SCORE>
__global__ __launch_bounds__(256) void k_gather(const int* __restrict__ rowptr,
    const int* __restrict__ col, const float* __restrict__ dinv,
    const float* __restrict__ H, const float* __restrict__ bias,
    float* __restrict__ OUT, int M,
    const float* __restrict__ p, float* __restrict__ score){
  constexpr int FQ = F/4;
  int i = blockIdx.x*256+threadIdx.x;
  if (i >= M*FQ) return;
  int n = i/FQ, q = i - (i/FQ)*FQ;
  int beg = rowptr[n], end = rowptr[n+1];
  float4 acc; acc.x=0.f;acc.y=0.f;acc.z=0.f;acc.w=0.f;
  for (int j=beg;j<end;++j){
    int s = col[j];
    float c = dinv[s];
    float4 h = *(const float4*)(H + (size_t)s*F + q*4);
    acc.x=fmaf(c,h.x,acc.x); acc.y=fmaf(c,h.y,acc.y);
    acc.z=fmaf(c,h.z,acc.z); acc.w=fmaf(c,h.w,acc.w);
  }
  float dn = dinv[n];
  float sc = 2.f*dn*dn;
  float4 hn = *(const float4*)(H + (size_t)n*F + q*4);
  float4 bv = *(const float4*)(bias + q*4);
  float4 o;
  o.x = eluf(fmaf(sc,hn.x,fmaf(dn,acc.x,bv.x)));
  o.y = eluf(fmaf(sc,hn.y,fmaf(dn,acc.y,bv.y)));
  o.z = eluf(fmaf(sc,hn.z,fmaf(dn,acc.z,bv.z)));
  o.w = eluf(fmaf(sc,hn.w,fmaf(dn,acc.w,bv.w)));
  *(float4*)(OUT + (size_t)n*F + q*4) = o;
  if (SCORE){
    float4 pv = *(const float4*)(p + q*4);
    float dot = o.x*pv.x + o.y*pv.y + o.z*pv.z + o.w*pv.w;
    float n2  = pv.x*pv.x + pv.y*pv.y + pv.z*pv.z + pv.w*pv.w;
    #pragma unroll
    for (int mk=FQ>>1; mk>0; mk>>=1){
      dot += __shfl_xor(dot, mk);
      n2  += __shfl_xor(n2,  mk);
    }
    if (q==0) score[n] = tanhf(dot * rsqrtf(n2));
  }
}

// ---- pooled-level GCN aggregation through rm filter; optional fused score
template<int F, bool SCORE>
__global__ __launch_bounds__(256) void k_gather_rm(const int* __restrict__ orig,
    const int* __restrict__ rowptr0, const int* __restrict__ col0,
    const int* __restrict__ rm, const float* __restrict__ dinv,
    const float* __restrict__ H, const float* __restrict__ bias,
    float* __restrict__ OUT, int M,
    const float* __restrict__ p, float* __restrict__ score){
  constexpr int FQ = F/4;
  int i = blockIdx.x*256+threadIdx.x;
  if (i >= M*FQ) return;
  int n = i/FQ, q = i - (i/FQ)*FQ;
  int o = orig[n];
  int beg = rowptr0[o], end = rowptr0[o+1];
  float4 acc; acc.x=0.f;acc.y=0.f;acc.z=0.f;acc.w=0.f;
  for (int j=beg;j<end;++j){
    int s = rm[col0[j]];
    if (s >= 0){
      float c = dinv[s];
      float4 h = *(const float4*)(H + (size_t)s*F + q*4);
      acc.x=fmaf(c,h.x,acc.x); acc.y=fmaf(c,h.y,acc.y);
      acc.z=fmaf(c,h.z,acc.z); acc.w=fmaf(c,h.w,acc.w);
    }
  }
  float dn = dinv[n];
  float sc = 2.f*dn*dn;
  float4 hn = *(const float4*)(H + (size_t)n*F + q*4);
  float4 bv = *(const float4*)(bias + q*4);
  float4 ov;
  ov.x = eluf(fmaf(sc,hn.x,fmaf(dn,acc.x,bv.x)));
  ov.y = eluf(fmaf(sc,hn.y,fmaf(dn,acc.y,bv.y)));
  ov.z = eluf(fmaf(sc,hn.z,fmaf(dn,acc.z,bv.z)));
  ov.w = eluf(fmaf(sc,hn.w,fmaf(dn,acc.w,bv.w)));
  *(float4*)(OUT + (size_t)n*F + q*4) = ov;
  if (SCORE){
    float4 pv = *(const float4*)(p + q*4);
    float dot = ov.x*pv.x + ov.y*pv.y + ov.z*pv.z + ov.w*pv.w;
    float n2  = pv.x*pv.x + pv.y*pv.y + pv.z*pv.z + pv.w*pv.w;
    #pragma unroll
    for (int mk=FQ>>1; mk>0; mk>>=1){
      dot += __shfl_xor(dot, mk);
      n2  += __shfl_xor(n2,  mk);
    }
    if (q==0) score[n] = tanhf(dot * rsqrtf(n2));
  }
}

// block g sorts its npg scores descending (tie: lower index first), writes top-K
__global__ void k_topk(const float* __restrict__ score, int npg, int K,
                       int* __restrict__ perm, float* __restrict__ vals){
  __shared__ float ss[1024]; __shared__ int si[1024];
  int g = blockIdx.x, tid = threadIdx.x;
  ss[tid] = score[g*npg + tid]; si[tid] = tid;
  __syncthreads();
  for (int k=2;k<=npg;k<<=1){
    for (int j=k>>1;j>0;j>>=1){
      int ixj = tid ^ j;
      if (ixj > tid){
        float s1=ss[tid], s2=ss[ixj]; int i1=si[tid], i2=si[ixj];
        bool aAfterB = (s1 < s2) || (s1==s2 && i1 > i2);
        bool sw = ((tid & k)==0) ? aAfterB : !aAfterB;
        if (sw){ ss[tid]=s2; si[tid]=i2; ss[ixj]=s1; si[ixj]=i1; }
      }
      __syncthreads();
    }
  }
  if (tid < K){ perm[g*K+tid] = g*npg + si[tid]; vals[g*K+tid] = ss[tid]; }
}

__global__ void k_remap_set(const int* __restrict__ perm, int* __restrict__ remap, int n){
  int i = blockIdx.x*256+threadIdx.x; if (i<n) remap[perm[i]] = i;
}

// per-graph global max/mean pool over (1024,32), then MLP head + log_softmax
__global__ void k_head(const float* __restrict__ x13, const float* __restrict__ Wl,
                       const float* __restrict__ Wc, const float* __restrict__ bc,
                       float* __restrict__ out){
  __shared__ float smax[256], ssum[256];
  __shared__ float gv[64], g2[64], logit[10];
  int g = blockIdx.x, t = threadIdx.x;
  int f = t & 31, r0 = t >> 5;
  float mx = -3.4e38f, sm = 0.f;
  const float* base = x13 + (size_t)g*N_*32;
  for (int r=r0; r<N_; r+=8){ float v = base[r*32+f]; mx = fmaxf(mx,v); sm += v; }
  smax[t]=mx; ssum[t]=sm; __syncthreads();
  if (t<128){ smax[t]=fmaxf(smax[t],smax[t+128]); ssum[t]+=ssum[t+128]; } __syncthreads();
  if (t<64){ smax[t]=fmaxf(smax[t],smax[t+64]); ssum[t]+=ssum[t+64]; } __syncthreads();
  if (t<32){
    float m2 = fmaxf(smax[t],smax[t+32]); float s2 = ssum[t]+ssum[t+32];
    gv[t] = eluf(m2); gv[32+t] = eluf(s2 * (1.f/N_));
  }
  __syncthreads();
  if (t<64){
    float acc=0.f;
    #pragma unroll
    for (int i2=0;i2<64;++i2) acc = fmaf(gv[i2], Wl[i2*64+t], acc);
    g2[t] = eluf(acc);
  }
  __syncthreads();
  if (t<10){
    float acc = bc[t];
    #pragma unroll
    for (int j=0;j<64;++j) acc = fmaf(g2[j], Wc[j*10+t], acc);
    logit[t] = acc;
  }
  __syncthreads();
  if (t==0){
    float m=-3.4e38f; for (int c=0;c<10;++c) m=fmaxf(m,logit[c]);
    float s=0.f; for (int c=0;c<10;++c) s += expf(logit[c]-m);
    float lse = m + logf(s);
    for (int c=0;c<10;++c) out[g*10+c] = logit[c]-lse;
  }
}

extern "C" void kernel_launch(void* const* d_in, const int* in_sizes, int n_in,
                              void* d_out, int out_size, void* d_ws, size_t ws_size,
                              hipStream_t stream){
  const float* x  = (const float*)d_in[0];
  const float* W1 = (const float*)d_in[1];
  const float* b1 = (const float*)d_in[2];
  const float* p1 = (const float*)d_in[3];
  const float* W2 = (const float*)d_in[4];
  const float* b2 = (const float*)d_in[5];
  const float* p2 = (const float*)d_in[6];
  const float* W3 = (const float*)d_in[7];
  const float* b3 = (const float*)d_in[8];
  const float* p3 = (const float*)d_in[9];
  const float* W4 = (const float*)d_in[10];
  const float* b4 = (const float*)d_in[11];
  const float* W5 = (const float*)d_in[12];
  const float* b5 = (const float*)d_in[13];
  const float* W6 = (const float*)d_in[14];
  const float* b6 = (const float*)d_in[15];
  const float* W7 = (const float*)d_in[16];
  const float* b7 = (const float*)d_in[17];
  const float* Wl = (const float*)d_in[18];
  const float* Wc = (const float*)d_in[19];
  const float* bc = (const float*)d_in[20];
  const int* src0 = (const int*)d_in[21];
  const int* dst0 = (const int*)d_in[22];
  float* out = (float*)d_out;

  char* wsp = (char*)d_ws;
  size_t off = 0;
  auto alloc = [&](size_t bytes)->char*{
    char* p = wsp + off;
    off += (bytes + 255) & ~(size_t)255;
    return p;
  };
  float* bufA = (float*)alloc((size_t)2097152*4);   // x1 / x13
  float* bufB = (float*)alloc((size_t)2097152*4);   // x3
  float* bufC = (float*)alloc((size_t)2097152*4);   // x5 / x11
  float* bufD = (float*)alloc((size_t)2097152*4);   // x7 / x9
  float* bufH = (float*)alloc((size_t)2097152*4);   // pre-norm H
  float* score= (float*)alloc((size_t)M0_*4);
  float* vals2= (float*)alloc((size_t)M1_*4);
  float* vals4= (float*)alloc((size_t)M2_*4);
  float* vals6= (float*)alloc((size_t)M3_*4);
  int* idx2 = (int*)alloc((size_t)M1_*4);   // level2 -> level0
  int* idx4 = (int*)alloc((size_t)M2_*4);   // level4 -> level2
  int* idx6 = (int*)alloc((size_t)M3_*4);   // level6 -> level4
  int* orig4 = (int*)alloc((size_t)M2_*4);  // level4 -> level0
  int* orig6 = (int*)alloc((size_t)M3_*4);  // level6 -> level0
  int* rm02 = (int*)alloc((size_t)M0_*4);
  int* rm04 = (int*)alloc((size_t)M0_*4);
  int* rm06 = (int*)alloc((size_t)M0_*4);
  int* col0 = (int*)alloc((size_t)E_*4);
  int* rowptr0 = (int*)alloc((size_t)(M0_+1)*4);
  int* cursor0 = (int*)alloc((size_t)M0_*4);
  int* degi0 = (int*)alloc((size_t)M0_*4);
  int* bsum  = (int*)alloc((size_t)256*4);
  float* dinv0 = (float*)alloc((size_t)M0_*4);
  float* dinv2 = (float*)alloc((size_t)M1_*4);
  float* dinv4 = (float*)alloc((size_t)M2_*4);
  float* dinv6 = (float*)alloc((size_t)M3_*4);

  auto NB = [](int total){ return (total+255)/256; };

  // ---- level-0 CSR (shared by layers 1 and 7)
  hipMemsetAsync(degi0, 0, (size_t)M0_*4, stream);
  k_deg0<<<NB(E_),256,0,stream>>>(dst0, degi0);
  k_scanA<<<256,256,0,stream>>>(degi0, bsum);
  k_scanB<<<1,256,0,stream>>>(bsum);
  k_scanC<<<256,256,0,stream>>>(degi0, bsum, rowptr0, cursor0, dinv0);
  k_place0<<<NB(E_),256,0,stream>>>(src0, dst0, cursor0, col0);

  // ---- layer 1: gcn(x) -> x1 (bufA) + fused score1
  k_mm<64,32,0><<<dim3(M0_/64,1),256,0,stream>>>(x, W1, bufH, M0_, 128, 32,
      nullptr,nullptr,nullptr,nullptr,nullptr,0);
  k_gather<32,true><<<NB(M0_*8),256,0,stream>>>(rowptr0, col0, dinv0, bufH, b1, bufA, M0_, p1, score);

  // ---- pool 1
  k_topk<<<B_,1024,0,stream>>>(score, 1024, K1_, idx2, vals2);
  hipMemsetAsync(rm02, 0xFF, (size_t)M0_*4, stream);
  k_remap_set<<<NB(M1_),256,0,stream>>>(idx2, rm02, M1_);
  k_deg_orig<<<NB(M1_),256,0,stream>>>(idx2, rowptr0, col0, rm02, dinv2, M1_);

  // ---- layer 2 (X = fused pool of x1) -> x3 (bufB) + fused score2
  k_mm<64,32,1><<<dim3(M1_/64,2),256,0,stream>>>(bufA, W2, bufH, M1_, 32, 64,
      idx2, vals2, nullptr,nullptr,nullptr,0);
  k_gather_rm<64,true><<<NB(M1_*16),256,0,stream>>>(idx2, rowptr0, col0, rm02, dinv2, bufH, b2, bufB, M1_, p2, score);

  // ---- pool 2
  k_topk<<<B_,512,0,stream>>>(score, 512, K2_, idx4, vals4);
  k_compose_idx<<<NB(M2_),256,0,stream>>>(idx2, idx4, orig4, M2_);
  hipMemsetAsync(rm04, 0xFF, (size_t)M0_*4, stream);
  k_remap_set<<<NB(M2_),256,0,stream>>>(orig4, rm04, M2_);
  k_deg_orig<<<NB(M2_),256,0,stream>>>(orig4, rowptr0, col0, rm04, dinv4, M2_);

  // ---- layer 3 -> x5 (bufC) + fused score3
  k_mm<64,32,1><<<dim3(M2_/64,4),256,0,stream>>>(bufB, W3, bufH, M2_, 64, 128,
      idx4, vals4, nullptr,nullptr,nullptr,0);
  k_gather_rm<128,true><<<NB(M2_*32),256,0,stream>>>(orig4, rowptr0, col0, rm04, dinv4, bufH, b3, bufC, M2_, p3, score);

  // ---- pool 3
  k_topk<<<B_,256,0,stream>>>(score, 256, K3_, idx6, vals6);
  k_compose_idx<<<NB(M3_),256,0,stream>>>(orig4, idx6, orig6, M3_);
  hipMemsetAsync(rm06, 0xFF, (size_t)M0_*4, stream);
  k_remap_set<<<NB(M3_),256,0,stream>>>(orig6, rm06, M3_);
  k_deg_orig<<<NB(M3_),256,0,stream>>>(orig6, rowptr0, col0, rm06, dinv6, M3_);

  // ---- layer 4 -> x7 (bufD)
  k_mm<64,32,1><<<dim3(M3_/64,8),256,0,stream>>>(bufC, W4, bufH, M3_, 128, 256,
      idx6, vals6, nullptr,nullptr,nullptr,0);
  k_gather_rm<256,false><<<NB(M3_*64),256,0,stream>>>(orig6, rowptr0, col0, rm06, dinv6, bufH, b4, bufD, M3_, nullptr, nullptr);

  // ---- layer 5 (X = fused concat(x7 scattered, x5)) -> x9 (bufD)
  k_mm<64,32,2><<<dim3(M2_/64,4),256,0,stream>>>(bufC, W5, bufH, M2_, 384, 128,
      nullptr,nullptr, bufD, orig4, rm06, 64);
  k_gather_rm<128,false><<<NB(M2_*32),256,0,stream>>>(orig4, rowptr0, col0, rm04, dinv4, bufH, b5, bufD, M2_, nullptr, nullptr);

  // ---- layer 6 (X = fused concat(x9 scattered, x3)) -> x11 (bufC)
  k_mm<64,32,2><<<dim3(M1_/64,2),256,0,stream>>>(bufB, W6, bufH, M1_, 192, 64,
      nullptr,nullptr, bufD, idx2, rm04, 32);
  k_gather_rm<64,false><<<NB(M1_*16),256,0,stream>>>(idx2, rowptr0, col0, rm02, dinv2, bufH, b6, bufC, M1_, nullptr, nullptr);

  // ---- layer 7 (X = fused concat(x11 scattered, x1)) -> x13 (bufA)
  k_mm<64,32,2><<<dim3(M0_/64,1),256,0,stream>>>(bufA, W7, bufH, M0_, 96, 32,
      nullptr,nullptr, bufC, nullptr, rm02, 16);
  k_gather<32,false><<<NB(M0_*8),256,0,stream>>>(rowptr0, col0, dinv0, bufH, b7, bufA, M0_, nullptr, nullptr);

  // ---- head
  k_head<<<B_,256,0,stream>>>(bufA, Wl, Wc, bc, out);

  (void)in_sizes; (void)n_in; (void)out_size; (void)ws_size;
}